// Round 7
// baseline (171.104 us; speedup 1.0000x reference)
//
#include <hip/hip_runtime.h>
#include <math.h>

#define B_ 8
#define T_ 256
#define IDIM_ 128
#define ODIM_ 128
#define HDIM_ 512
#define CDIM_ 128
#define NROWS_ (B_*T_)
#define TEMPER_ 5.0f
#define ENERGY_TH_ 100.0f
#define N_ITER_ 4
#define XPAD_ 384   // [0,127) zeros | [127,255) x | [255,384) zeros
#define RPB_ 4      // rows per block, 2 waves each -> 512 threads
#define NBLK_ (NROWS_/RPB_)

struct Ws {
  unsigned cnt_y_nz;
  unsigned cnt_rows_nm;
  double partial[NBLK_][N_ITER_];   // per-block loss partials (plain stores)
};

// 8 blocks x 256 threads; one row per thread
__global__ __launch_bounds__(256) void k_count(const float* __restrict__ y,
                                               Ws* __restrict__ h) {
  __shared__ unsigned redn[256];
  __shared__ unsigned redr[256];
  const int tid = threadIdx.x;
  const int row = blockIdx.x * 256 + tid;
  const float4* yr = (const float4*)(y + row * ODIM_);
  unsigned c = 0;
  #pragma unroll 8
  for (int i = 0; i < 32; ++i) {
    float4 v = yr[i];
    c += (v.x != 0.f) + (v.y != 0.f) + (v.z != 0.f) + (v.w != 0.f);
  }
  redn[tid] = c;
  redr[tid] = (c > 0u) ? 1u : 0u;
  __syncthreads();
  for (int off = 128; off > 0; off >>= 1) {
    if (tid < off) { redn[tid] += redn[tid + off]; redr[tid] += redr[tid + off]; }
    __syncthreads();
  }
  if (tid == 0) {
    atomicAdd(&h->cnt_y_nz, redn[0]);
    atomicAdd(&h->cnt_rows_nm, redr[0]);
  }
}

__device__ inline float wsum(float p) {
  #pragma unroll
  for (int off = 32; off; off >>= 1) p += __shfl_xor(p, off, 64);
  return p;
}
__device__ inline float wmaxf(float p) {
  #pragma unroll
  for (int off = 32; off; off >>= 1) p = fmaxf(p, __shfl_xor(p, off, 64));
  return p;
}
__device__ inline void pick(float& v, int& i, float v2, int i2) {
  if (v2 > v || (v2 == v && i2 < i)) { v = v2; i = i2; }
}

// ---- radix-select: top-CDIM_ of 512 keys (8/lane, elem c = lane + 64k).
// 64-bin (6-bit digit) passes, lane l owns bin l. Early-exit when the
// boundary bucket is fully consumed (rem_new == h_b): cut is crisp at the
// bucket floor F -> selection == {key >= F} == {key > F-1}, rem = 0.
// Identical selected set to full-resolution radix (no cross-boundary ties
// possible when count(key>=F) == 128 exactly).
__device__ inline void radix_topk(const unsigned* key, unsigned* s_hist,
                                  int l, unsigned& t_out, int& rem_out) {
  unsigned prefix = 0u;
  unsigned hi_mask = 0u;
  int rem = CDIM_;
  int shift = 26;
  #pragma unroll 1
  for (int pass = 0; pass < 6; ++pass) {
    const int width = (shift == 0) ? 2 : 6;
    const unsigned nb = 1u << width;
    s_hist[l] = 0u;
    __threadfence_block();
    #pragma unroll
    for (int k = 0; k < 8; ++k) {
      if ((key[k] & hi_mask) == prefix)
        atomicAdd(&s_hist[(key[k] >> shift) & (nb - 1u)], 1u);
    }
    __threadfence_block();
    unsigned h = s_hist[l];
    // inclusive suffix scan over lanes: s_l = sum_{j>=l} h_j
    unsigned s = h;
    #pragma unroll
    for (int off = 1; off < 64; off <<= 1) {
      unsigned o = __shfl(s, min(l + off, 63), 64);
      s += (l + off < 64) ? o : 0u;
    }
    unsigned suf = s - h;
    unsigned r = (unsigned)rem;
    bool isb = (suf < r) && (r <= s);
    unsigned long long bm = __ballot(isb);
    int b = __ffsll((unsigned long long)bm) - 1;   // boundary bin (uniform)
    unsigned h_b   = __shfl(h,   b, 64);
    unsigned suf_b = __shfl(suf, b, 64);
    unsigned rem_new = r - suf_b;
    prefix |= ((unsigned)b) << shift;
    hi_mask |= (nb - 1u) << shift;
    rem = (int)rem_new;
    if (rem_new == h_b && prefix != 0u) {     // crisp cut at bucket floor
      t_out = prefix - 1u;
      rem_out = 0;
      return;
    }
    if (shift == 0) break;
    shift -= 6; if (shift < 0) shift = 0;
  }
  t_out = prefix;     // full 32-bit threshold; ties broken by index via rem
  rem_out = rem;
}

__global__ __launch_bounds__(512, 2) void k_main(
    const float* __restrict__ gx, const float* __restrict__ gy,
    const float* __restrict__ enc_w, const float* __restrict__ enc_b,
    const float* __restrict__ dec_w, const float* __restrict__ dec_b,
    Ws* __restrict__ hdr)
{
  const int tid = threadIdx.x;
  const int wid = tid >> 6;     // 0..7
  const int l   = tid & 63;
  const int r   = wid >> 1;     // row-in-block 0..3
  const int sub = wid & 1;      // wave within pair
  const int row = blockIdx.x * RPB_ + r;

  __shared__ __align__(16) float s_xpad[RPB_][XPAD_];
  __shared__ __align__(16) float s_y[RPB_][ODIM_];
  __shared__ __align__(16) float s_yatt[RPB_][ODIM_];
  __shared__ __align__(16) float s_h[RPB_][HDIM_];
  __shared__ __align__(16) float s_dot[RPB_][2][256];
  __shared__ __align__(16) float s_nx[RPB_][2][256];
  __shared__ float s_dpart[RPB_][2][ODIM_];
  __shared__ float s_scal[RPB_][2];
  __shared__ unsigned s_hist[RPB_][64];
  __shared__ unsigned long long s_pack[RPB_][CDIM_];
  __shared__ double s_loss[RPB_][N_ITER_];

  float* m_xpad = s_xpad[r];
  float* m_y    = s_y[r];
  unsigned* m_hist = s_hist[r];
  unsigned long long* m_pack = s_pack[r];

  const unsigned long long lmask_lt = (l == 0) ? 0ull : ((1ull << l) - 1ull);
  const float* gxr = gx + row * IDIM_;
  const float* gyr = gy + row * ODIM_;

  // init: pair splits xpad; sub0 owns y registers + y LDS
  for (int t = l + 64 * sub; t < XPAD_; t += 128)
    m_xpad[t] = (t >= 127 && t < 127 + IDIM_) ? gxr[t - 127] : 0.f;

  float y0 = 0.f, y1 = 0.f;
  bool sq0 = false, sq1 = false, sm_row = false;
  if (sub == 0) {
    y0 = gyr[l]; y1 = gyr[l + 64];
    m_y[l] = y0; m_y[l + 64] = y1;
    sq0 = (y0 == 0.f); sq1 = (y1 == 0.f);
    sm_row = (__ballot((!sq0) || (!sq1)) == 0ull);
  }
  const float denom_ll = (float)max(hdr->cnt_y_nz, 1u);
  const float denomh   = (float)max(hdr->cnt_rows_nm * (unsigned)HDIM_, 1u);

  int mprev[8];
  #pragma unroll
  for (int k = 0; k < 8; ++k) mprev[k] = 0;

  int theta = 0;
  float row_lh = 0.f;

  __syncthreads();

  for (int iter = 0; iter < N_ITER_; ++iter) {
    // ========== P0: sim partials (each wave: half the j-range) ==========
    {
      const int jbase = 64 * sub;
      float yv = m_y[jbase + l];
      float pn = wsum(yv * yv);
      if (l == 0) s_scal[r][sub] = pn;

      float dot0 = 0, dot1 = 0, dot2 = 0, dot3 = 0;
      float nx0 = 0, nx1 = 0, nx2 = 0, nx3 = 0;
      const int m4 = 4 * l;
      float4 xq0 = *(const float4*)&m_xpad[m4 + jbase];
      #pragma unroll 4
      for (int jb = 0; jb < 16; ++jb) {
        float4 yq  = *(const float4*)&m_y[jbase + 4 * jb];
        float4 xq1 = *(const float4*)&m_xpad[m4 + jbase + 4 * jb + 4];
        float xa = xq0.x, xb = xq0.y, xc = xq0.z, xd = xq0.w;
        float xe_ = xq1.x, xf = xq1.y, xg = xq1.z;
        dot0 += xa * yq.x; nx0 += xa * xa; dot0 += xb * yq.y; nx0 += xb * xb;
        dot0 += xc * yq.z; nx0 += xc * xc; dot0 += xd * yq.w; nx0 += xd * xd;
        dot1 += xb * yq.x; nx1 += xb * xb; dot1 += xc * yq.y; nx1 += xc * xc;
        dot1 += xd * yq.z; nx1 += xd * xd; dot1 += xe_ * yq.w; nx1 += xe_ * xe_;
        dot2 += xc * yq.x; nx2 += xc * xc; dot2 += xd * yq.y; nx2 += xd * xd;
        dot2 += xe_ * yq.z; nx2 += xe_ * xe_; dot2 += xf * yq.w; nx2 += xf * xf;
        dot3 += xd * yq.x; nx3 += xd * xd; dot3 += xe_ * yq.y; nx3 += xe_ * xe_;
        dot3 += xf * yq.z; nx3 += xf * xf; dot3 += xg * yq.w; nx3 += xg * xg;
        xq0 = xq1;
      }
      float4 dq = {dot0, dot1, dot2, dot3};
      float4 nq = {nx0, nx1, nx2, nx3};
      *(float4*)&s_dot[r][sub][m4] = dq;
      *(float4*)&s_nx[r][sub][m4]  = nq;
    }
    __syncthreads();

    // ========== P1 (sub0): combine + argmax + softmax ==========
    if (sub == 0) {
      const float normy = sqrtf(s_scal[r][0] + s_scal[r][1]);
      float4 dA = *(const float4*)&s_dot[r][0][4 * l];
      float4 dB = *(const float4*)&s_dot[r][1][4 * l];
      float4 nA = *(const float4*)&s_nx[r][0][4 * l];
      float4 nB = *(const float4*)&s_nx[r][1][4 * l];
      float dot0 = dA.x + dB.x, dot1 = dA.y + dB.y;
      float dot2 = dA.z + dB.z, dot3 = dA.w + dB.w;
      float nx0 = nA.x + nB.x, nx1 = nA.y + nB.y;
      float nx2 = nA.z + nB.z, nx3 = nA.w + nB.w;
      float den, sv, bestv; int besti;
      den = normy * sqrtf(nx0); sv = (den == 0.f) ? 0.f : dot0 / den;
      bestv = sv; besti = 4 * l;
      den = normy * sqrtf(nx1); sv = (den == 0.f) ? 0.f : dot1 / den;
      pick(bestv, besti, sv, 4 * l + 1);
      den = normy * sqrtf(nx2); sv = (den == 0.f) ? 0.f : dot2 / den;
      pick(bestv, besti, sv, 4 * l + 2);
      if (4 * l + 3 < 255) {
        den = normy * sqrtf(nx3); sv = (den == 0.f) ? 0.f : dot3 / den;
        pick(bestv, besti, sv, 4 * l + 3);
      }
      #pragma unroll
      for (int off = 32; off; off >>= 1) {
        float ov = __shfl_xor(bestv, off, 64);
        int   oi = __shfl_xor(besti, off, 64);
        pick(bestv, besti, ov, oi);
      }
      theta = besti;

      float yal0 = m_xpad[theta + l];
      float yal1 = m_xpad[theta + l + 64];
      float z0 = yal0 * y0 / TEMPER_;
      float z1 = yal1 * y1 / TEMPER_;
      float zmax = wmaxf(fmaxf(z0, z1));
      float e0 = expf(z0 - zmax), e1 = expf(z1 - zmax);
      float esum = wsum(e0 + e1);
      s_yatt[r][l]      = yal0 * (e0 / esum);
      s_yatt[r][l + 64] = yal1 * (e1 / esum);
    }
    __syncthreads();

    // ========== P2 (all 512 threads): h[r'] = y_att[r'] @ enc_w + enc_b ====
    // 16-deep weight chunks: 16 loads in flight per wait
    {
      const int c = tid;                    // one column per thread
      const float* wp = enc_w + c;
      float a0 = 0.f, a1 = 0.f, a2 = 0.f, a3 = 0.f;
      #pragma unroll 1
      for (int ch = 0; ch < 8; ++ch) {
        float w[16];
        #pragma unroll
        for (int k = 0; k < 16; ++k) w[k] = wp[(16 * ch + k) * HDIM_];
        #pragma unroll
        for (int q = 0; q < 4; ++q) {
          float4 ya0q = *(const float4*)&s_yatt[0][16 * ch + 4 * q];
          float4 ya1q = *(const float4*)&s_yatt[1][16 * ch + 4 * q];
          float4 ya2q = *(const float4*)&s_yatt[2][16 * ch + 4 * q];
          float4 ya3q = *(const float4*)&s_yatt[3][16 * ch + 4 * q];
          #pragma unroll
          for (int u = 0; u < 4; ++u) {
            float wv = w[4 * q + u];
            a0 += ((const float*)&ya0q)[u] * wv;
            a1 += ((const float*)&ya1q)[u] * wv;
            a2 += ((const float*)&ya2q)[u] * wv;
            a3 += ((const float*)&ya3q)[u] * wv;
          }
        }
      }
      float eb = enc_b[c];
      s_h[0][c] = a0 + eb;
      s_h[1][c] = a1 + eb;
      s_h[2][c] = a2 + eb;
      s_h[3][c] = a3 + eb;
    }
    __syncthreads();

    // ========== P3 (sub0): hsr radix + pack ==========
    if (sub == 0) {
      float hv[8]; unsigned key[8];
      #pragma unroll
      for (int k = 0; k < 8; ++k) {
        hv[k] = s_h[r][l + 64 * k];
        key[k] = __float_as_uint(hv[k] * hv[k]);
      }
      row_lh = 0.f;
      if (iter > 0) {
        unsigned t0; int rem0;
        radix_topk(key, m_hist, l, t0, rem0);
        int eqbefore = 0; float lacc = 0.f;
        #pragma unroll
        for (int k = 0; k < 8; ++k) {
          bool eq = (key[k] == t0);
          unsigned long long beq = __ballot(eq);
          int rank = eqbefore + __popcll(beq & lmask_lt);
          bool sel0 = (key[k] > t0) || (eq && rank < rem0);
          eqbefore += __popcll(beq);
          if (sel0 && mprev[k] > 0 && !sm_row) {
            float d = hv[k] - (1.f - (float)mprev[k]);
            lacc += (d * d) / denomh;
          }
        }
        row_lh = wsum(lacc);
        #pragma unroll
        for (int k = 0; k < 8; ++k) {
          if (mprev[k] > 0) hv[k] = 0.f;
          key[k] = __float_as_uint(hv[k] * hv[k]);
        }
      }
      unsigned t; int rem;
      radix_topk(key, m_hist, l, t, rem);
      int scount = 0, eqbefore = 0;
      #pragma unroll
      for (int k = 0; k < 8; ++k) {
        bool eq = (key[k] == t);
        unsigned long long beq = __ballot(eq);
        int rank = eqbefore + __popcll(beq & lmask_lt);
        bool sel = (key[k] > t) || (eq && rank < rem);
        eqbefore += __popcll(beq);
        unsigned long long mk = __ballot(sel);
        if (sel) {
          int pos = scount + __popcll(mk & lmask_lt);
          m_pack[pos] = (((unsigned long long)__float_as_uint(hv[k])) << 32)
                        | (unsigned)(l + 64 * k);
          mprev[k] += 1;
        }
        scount += (int)__popcll(mk);
      }
    }
    __syncthreads();

    // ========== P4: dec partials (each wave: 64 selected channels) ==========
    // 16-deep scalar chunks (48 live regs) -- fits VGPR cap, no spill
    {
      float acc0 = 0.f, acc1 = 0.f;
      #pragma unroll 1
      for (int ch = 0; ch < 4; ++ch) {
        float hj[16], w0[16], w1[16];
        #pragma unroll
        for (int j = 0; j < 16; ++j) {
          unsigned long long pk = m_pack[64 * sub + 16 * ch + j];
          hj[j] = __uint_as_float((unsigned)(pk >> 32));
          const float* p = dec_w + (unsigned)(pk & 0xffffffffull) * (unsigned)ODIM_;
          w0[j] = p[l];
          w1[j] = p[l + 64];
        }
        #pragma unroll
        for (int j = 0; j < 16; ++j) {
          acc0 += hj[j] * w0[j];
          acc1 += hj[j] * w1[j];
        }
      }
      s_dpart[r][sub][l]      = acc0;
      s_dpart[r][sub][l + 64] = acc1;
    }
    __syncthreads();

    // ========== P5 (sub0): y_ele, loss, residuals ==========
    if (sub == 0) {
      float ye0 = (s_dpart[r][0][l]      + s_dpart[r][1][l])      + dec_b[l];
      float ye1 = (s_dpart[r][0][l + 64] + s_dpart[r][1][l + 64]) + dec_b[l + 64];

      float tshift  = fabsf((float)theta - 127.f);
      float menergy = tshift + 1.f;
      bool  mmask   = (tshift > ENERGY_TH_);
      float d0 = ye0 - y0, d1 = ye1 - y1;
      float ll0 = sq0 ? 0.f : d0 * d0; ll0 /= denom_ll; ll0 = mmask ? 0.f : ll0; ll0 /= menergy;
      float ll1 = sq1 ? 0.f : d1 * d1; ll1 /= denom_ll; ll1 = mmask ? 0.f : ll1; ll1 /= menergy;
      float row_ll = wsum(ll0 + ll1);
      if (l == 0) s_loss[r][iter] = (double)(row_ll + row_lh);   // no atomics

      int src0 = l + 127 - theta;
      int src1 = l + 64 + 127 - theta;
      float xe0 = (src0 >= 0 && src0 < ODIM_) ? s_yatt[r][src0] : 0.f;
      float xe1 = (src1 >= 0 && src1 < ODIM_) ? s_yatt[r][src1] : 0.f;
      y0 -= ye0; y1 -= ye1;
      m_y[l] = y0; m_y[l + 64] = y1;
      m_xpad[127 + l]      -= xe0;
      m_xpad[127 + 64 + l] -= xe1;
    }
    __syncthreads();
  }

  // per-block partials: plain f64 stores, deterministic order (r ascending)
  if (tid < N_ITER_) {
    double s = ((s_loss[0][tid] + s_loss[1][tid]) + s_loss[2][tid]) + s_loss[3][tid];
    hdr->partial[blockIdx.x][tid] = s;
  }
}

__global__ __launch_bounds__(256) void k_finish(const Ws* __restrict__ hdr,
                                                float* __restrict__ out) {
  __shared__ double red[256];
  const int t = threadIdx.x;
  const double* p0 = &hdr->partial[t][0];
  const double* p1 = &hdr->partial[t + 256][0];
  double s = ((p0[0] + p0[1]) + (p0[2] + p0[3]))
           + ((p1[0] + p1[1]) + (p1[2] + p1[3]));
  red[t] = s;
  __syncthreads();
  for (int off = 128; off > 0; off >>= 1) {
    if (t < off) red[t] += red[t + off];
    __syncthreads();
  }
  if (t == 0) out[0] = (float)(red[0] * 0.25);
}

extern "C" void kernel_launch(void* const* d_in, const int* in_sizes, int n_in,
                              void* d_out, int out_size, void* d_ws, size_t ws_size,
                              hipStream_t stream) {
  (void)in_sizes; (void)n_in; (void)out_size; (void)ws_size;
  const float* x     = (const float*)d_in[0];
  const float* y     = (const float*)d_in[1];
  const float* enc_w = (const float*)d_in[2];
  const float* enc_b = (const float*)d_in[3];
  const float* dec_w = (const float*)d_in[4];
  const float* dec_b = (const float*)d_in[5];
  float* out = (float*)d_out;
  Ws* hdr = (Ws*)d_ws;

  hipMemsetAsync(d_ws, 0, 8, stream);   // zero the two counters only
  hipLaunchKernelGGL(k_count,  dim3(NROWS_ / 256), dim3(256), 0, stream, y, hdr);
  hipLaunchKernelGGL(k_main,   dim3(NBLK_), dim3(512), 0, stream,
                     x, y, enc_w, enc_b, dec_w, dec_b, hdr);
  hipLaunchKernelGGL(k_finish, dim3(1), dim3(256), 0, stream, hdr, out);
}